// Round 11
// baseline (162.970 us; speedup 1.0000x reference)
//
#include <hip/hip_runtime.h>

#define BATCH 16
#define CCH   256
#define WLEN  4096
#define OCH   256
#define KW    3
#define CK    768      // CCH*KW
#define WIN   96       // x-window floats per channel
#define CHUNK 32       // channels per K-chunk
#define NCHUNK 8       // CCH / CHUNK
#define SLD   102      // Sl row stride (shorts): 204 B = 51 dwords, ODD -> conflict-free
                       // (104's 52-dword stride gave bank=20*lane mod 32: 8-way write conflicts)

typedef short bf16x8 __attribute__((ext_vector_type(8)));
typedef float f32x4  __attribute__((ext_vector_type(4)));

__device__ inline short f2bf(float f) {
    union { float f; unsigned u; } v; v.f = f;
    unsigned r = v.u + 0x7FFFu + ((v.u >> 16) & 1u);   // RNE
    return (short)(r >> 16);
}

__device__ inline void gl_lds16(const void* g, void* l) {
    __builtin_amdgcn_global_load_lds(
        (const __attribute__((address_space(1))) unsigned int*)g,
        (__attribute__((address_space(3))) unsigned int*)l, 16, 0, 0);
}

template<int N> __device__ inline void vmwait() {
    if constexpr (N == 0)      asm volatile("s_waitcnt vmcnt(0)" ::: "memory");
    else if constexpr (N == 1) asm volatile("s_waitcnt vmcnt(1)" ::: "memory");
    else if constexpr (N == 2) asm volatile("s_waitcnt vmcnt(2)" ::: "memory");
    else if constexpr (N == 4) asm volatile("s_waitcnt vmcnt(4)" ::: "memory");
    else if constexpr (N == 6) asm volatile("s_waitcnt vmcnt(6)" ::: "memory");
    else if constexpr (N == 7) asm volatile("s_waitcnt vmcnt(7)" ::: "memory");
    else if constexpr (N == 8) asm volatile("s_waitcnt vmcnt(8)" ::: "memory");
}
__device__ inline void lgkm0() { asm volatile("s_waitcnt lgkmcnt(0)" ::: "memory"); }

// ---------------- kernel 1: weight fp32 [256][768] -> bf16 ----------------
__global__ void wconv_kernel(const float* __restrict__ w, short* __restrict__ wb) {
    int i = blockIdx.x * 256 + threadIdx.x;
    wb[i] = f2bf(w[i]);
}

// ---------------- fused kernel v12: v11 + odd-stride Sl (conflict-free LDS) ----------------
// EXACT v11 pipeline (71.6 us: tail-issued loadA/stage, full-flight DMA). One change:
// SLD 104 -> 102 shorts. Odd dword stride (51) spreads lane*SLD across all 32 banks:
// Sl writes 8-way -> free, b-frag reads ~2-way. 204B rows are only 4B-aligned, so all
// Sl I/O is dword-based (clang merges to ds_read2/write2_b32; b128 no longer legal).
__global__ __launch_bounds__(512, 4)
void deform_fused_kernel(const float* __restrict__ x,
                         const short* __restrict__ wb,
                         const float* __restrict__ off,
                         const float* __restrict__ msk,
                         const float* __restrict__ bias,
                         float* __restrict__ out) {
    __shared__ float WinS[3][CHUNK * WIN];   // 3 x 12288 B: chunk windows
    __shared__ short SlS[2][64 * SLD];       // 2 x 13056 B: gathered B-tile [w][96ck]

    const int t      = threadIdx.x;
    const int b      = blockIdx.x >> 6;
    const int wt     = blockIdx.x & 63;
    const int lane   = t & 63;
    const int wv     = t >> 6;
    const int lr     = lane & 15;
    const int lq     = lane >> 4;
    const int wstart = wt * 64 - 16;
    const int wg     = wt * 64 + lane;

    // ---- per-lane sampling params (identical math to validated kernel) ----
    int   li[3];
    float rw0[3], rw1[3];
#pragma unroll
    for (int k = 0; k < 3; ++k) {
        float o  = off[b * (KW * WLEN) + k * WLEN + wg];
        float m  = msk[b * (KW * WLEN) + k * WLEN + wg];
        float p  = (float)(wg - 1 + k) + o;
        float pf = floorf(p);
        float w1 = p - pf;
        int i0 = (int)pf;
        int i1 = i0 + 1;
        bool v0 = (i0 >= 0) & (i0 < WLEN);
        bool v1 = (i1 >= 0) & (i1 < WLEN);
        li[k]  = min(max(i0 - wstart, 0), WIN - 2);   // row[li], row[li+1] both in-window
        rw0[k] = v0 ? m * (1.0f - w1) : 0.0f;
        rw1[k] = v1 ? m * w1 : 0.0f;
    }

    const float* xb = x + (size_t)b * CCH * WLEN;

    // ---- staging source offsets (lane-static): 768 float4 slots per chunk ----
    const int sA = t;
    const int chA = sA / 24, oA = sA - chA * 24;
    const int jA  = min(max(wstart + oA * 4, 0), WLEN - 4);
    const int offA = chA * WLEN + jA;
    const int sB = 512 + t;
    const int chB = sB / 24, oB = sB - chB * 24;
    const int jB  = min(max(wstart + oB * 4, 0), WLEN - 4);
    const int offB = chB * WLEN + jB;

    f32x4 acc[2][4];
#pragma unroll
    for (int i = 0; i < 2; ++i)
#pragma unroll
        for (int j = 0; j < 4; ++j)
            acc[i][j] = (f32x4){0.f, 0.f, 0.f, 0.f};

    // ---- stage chunk c's windows into WinS[bufsel] (waves 0-3: 2 DMA, 4-7: 1 DMA) ----
    auto stage = [&](int c, int bufsel) {
        const float* src = xb + (size_t)c * CHUNK * WLEN;
        gl_lds16(src + offA, &WinS[bufsel][wv * 256]);
        if (wv < 4) gl_lds16(src + offB, &WinS[bufsel][2048 + wv * 256]);
    };

    // ---- gather: wave wv samples its 4 channels from WinS[wbuf] -> SlS[sbuf] ----
    auto gather = [&](int wbuf, int sbuf) {
        union { short s[12]; unsigned u[6]; } obuf;
#pragma unroll
        for (int dc = 0; dc < 4; ++dc) {
            const float* row = &WinS[wbuf][(wv * 4 + dc) * WIN];
#pragma unroll
            for (int k = 0; k < 3; ++k) {
                float v0 = row[li[k]];
                float v1 = row[li[k] + 1];
                obuf.s[dc * 3 + k] = f2bf(rw0[k] * v0 + rw1[k] * v1);
            }
        }
        unsigned* up = reinterpret_cast<unsigned*>(&SlS[sbuf][lane * SLD + wv * 12]);
#pragma unroll
        for (int j = 0; j < 6; ++j)
            up[j] = obuf.u[j];                // odd-stride rows: ds_write2_b32 pairs
    };

    // ---- A-loads for chunk c (6 x bf16x8 from L2-hot wb) into persistent af ----
    auto loadA = [&](int c, bf16x8* af) {
#pragma unroll
        for (int ks = 0; ks < 3; ++ks)
#pragma unroll
            for (int mt = 0; mt < 2; ++mt)
                af[ks * 2 + mt] = *reinterpret_cast<const bf16x8*>(
                    wb + (size_t)(wv * 32 + mt * 16 + lr) * CK + c * 96 + ks * 32 + lq * 8);
    };

    // ---- MFMA with preloaded A-frags; B-frags via dword loads (ds_read2_b32) ----
    auto mfma_use = [&](const bf16x8* af, int sbuf) {
#pragma unroll
        for (int ks = 0; ks < 3; ++ks) {
            bf16x8 bfv[4];
#pragma unroll
            for (int nt = 0; nt < 4; ++nt) {
                const unsigned* p = reinterpret_cast<const unsigned*>(
                    &SlS[sbuf][(nt * 16 + lr) * SLD + ks * 32 + lq * 8]);
                union { unsigned u[4]; bf16x8 v; } r;
#pragma unroll
                for (int q = 0; q < 4; ++q)
                    r.u[q] = p[q];
                bfv[nt] = r.v;
            }
            __builtin_amdgcn_s_setprio(1);
#pragma unroll
            for (int mt = 0; mt < 2; ++mt)
#pragma unroll
                for (int nt = 0; nt < 4; ++nt)
                    acc[mt][nt] = __builtin_amdgcn_mfma_f32_16x16x32_bf16(
                        af[ks * 2 + mt], bfv[nt], acc[mt][nt], 0, 0, 0);
            __builtin_amdgcn_s_setprio(0);
        }
    };

    bf16x8 afA[6];

    // ---- prologue: af(0) first (oldest, drained free), stage 0,1,2; wait S(0) ----
    loadA(0, afA);
    stage(0, 0);
    stage(1, 1);
    stage(2, 2);
    if (wv < 4) vmwait<4>(); else vmwait<2>();   // S(0)+af(0) landed; S(1),S(2) in flight
    __builtin_amdgcn_s_barrier();
    gather(0, 0);

    // ---- iter 0: S(1) landed (only S(1),S(2) outstanding) ----
    if (wv < 4) vmwait<2>(); else vmwait<1>();
    lgkm0();
    __builtin_amdgcn_s_barrier();
    gather(1, 1);
    mfma_use(afA, 0);
    __builtin_amdgcn_sched_barrier(0);
    loadA(1, afA);                   // af BEFORE stage: af-wait never drains stage
    __builtin_amdgcn_sched_barrier(0);
    stage(3, 0);

    // ---- iters 1..4: ensure S(c+1) (oldest) landed, keep af(c)+S(c+2) in flight ----
#define ITER_MID(c)                                                    \
    if (wv < 4) vmwait<8>(); else vmwait<7>();                         \
    lgkm0();                                                           \
    __builtin_amdgcn_s_barrier();                                      \
    gather(((c) + 1) % 3, ((c) + 1) & 1);                              \
    mfma_use(afA, (c) & 1);                                            \
    __builtin_amdgcn_sched_barrier(0);                                 \
    loadA((c) + 1, afA);                                               \
    __builtin_amdgcn_sched_barrier(0);                                 \
    stage((c) + 3, (c) % 3);

    ITER_MID(1)
    ITER_MID(2)
    ITER_MID(3)
    ITER_MID(4)
#undef ITER_MID

    // ---- iter 5: last full pattern minus stage (S(7) was staged at iter 4) ----
    if (wv < 4) vmwait<8>(); else vmwait<7>();
    lgkm0();
    __builtin_amdgcn_s_barrier();
    gather(0, 0);                    // chunk 6 -> Win[0], Sl[0]
    mfma_use(afA, 1);
    __builtin_amdgcn_sched_barrier(0);
    loadA(6, afA);

    // ---- iter 6: outstanding [S(7), af(6)]: ensure S(7) ----
    vmwait<6>();
    lgkm0();
    __builtin_amdgcn_s_barrier();
    gather(1, 1);                    // chunk 7 -> Win[1], Sl[1]
    mfma_use(afA, 0);
    __builtin_amdgcn_sched_barrier(0);
    loadA(7, afA);

    // ---- iter 7 ----
    lgkm0();
    __builtin_amdgcn_s_barrier();
    mfma_use(afA, 1);

    // ---- epilogue: D row = lq*4+reg (oc), col = lr (w) ----
    float* ob = out + ((size_t)b * OCH) * WLEN + wt * 64;
#pragma unroll
    for (int mt = 0; mt < 2; ++mt) {
#pragma unroll
        for (int r = 0; r < 4; ++r) {
            int row = wv * 32 + mt * 16 + lq * 4 + r;
            float bv = bias[row];
            float* orow = ob + (size_t)row * WLEN + lr;
#pragma unroll
            for (int nt = 0; nt < 4; ++nt)
                orow[nt * 16] = acc[mt][nt][r] + bv;
        }
    }
}

extern "C" void kernel_launch(void* const* d_in, const int* in_sizes, int n_in,
                              void* d_out, int out_size, void* d_ws, size_t ws_size,
                              hipStream_t stream) {
    const float* x    = (const float*)d_in[0];
    const float* w    = (const float*)d_in[1];
    const float* off  = (const float*)d_in[2];
    const float* msk  = (const float*)d_in[3];
    const float* bias = (const float*)d_in[4];
    float* out = (float*)d_out;
    short* wb  = (short*)d_ws;   // 384 KB bf16 weights

    wconv_kernel<<<768, 256, 0, stream>>>(w, wb);
    deform_fused_kernel<<<BATCH * 64, 512, 0, stream>>>(x, wb, off, msk, bias, out);
}